// Round 27
// baseline (57.441 us; speedup 1.0000x reference)
//
#include <hip/hip_runtime.h>

#define B_   4
#define C_   64
#define H_   128
#define W_   128
#define KS   7
#define G_   4
#define GC_  16
#define KK   49
#define PAD  3
#define TH   8
#define TW   16
#define HW_  (H_ * W_)
#define ZKHB 2112              // bytes per kh plane: 128px*16B + 64B bank shift

// LDS layout (bytes): z [0, 14784) | w-tile [14784, 23488) | sc/sb
#define WOFF  14784            // w-tile [64k][68 bf16] stride 136B = 8704
#define SCOFF 23488            // folded scale, 49 f32
#define SBOFF 23688            // folded bias,  49 f32
#define LDSZ  23888

typedef float f32x4  __attribute__((ext_vector_type(4)));
typedef short bf16x8 __attribute__((ext_vector_type(8)));
typedef short bf16x4 __attribute__((ext_vector_type(4)));
typedef unsigned int u32x4 __attribute__((ext_vector_type(4)));
typedef __fp16 h16x2 __attribute__((ext_vector_type(2)));

__device__ __forceinline__ unsigned f2bf(float f) {
    unsigned u = __float_as_uint(f);
    unsigned r = u + 0x7FFFu + ((u >> 16) & 1u);
    return r >> 16;
}
__device__ __forceinline__ unsigned pk2(float a, float b) {
    union { h16x2 h; unsigned u; } x;
    x.h = __builtin_amdgcn_cvt_pkrtz(a, b);
    return x.u;
}
__device__ __forceinline__ h16x2 ash2(unsigned u) {
    union { unsigned u; h16x2 h; } x; x.u = u; return x.h;
}
__device__ __forceinline__ unsigned short f16b(float f) {
    union { __fp16 h; unsigned short s; } x; x.h = (__fp16)f; return x.s;
}
#if __has_builtin(__builtin_amdgcn_fdot2)
#define DOT2(a, b, c) __builtin_amdgcn_fdot2((a), (b), (c), false)
#else
#define DOT2(a, b, c) ((c) + (float)(a)[0] * (float)(b)[0] + (float)(a)[1] * (float)(b)[1])
#endif
#define AB(a, b) __builtin_amdgcn_alignbit((a), (b), 16)

// ---- involution phase macros: pure named-SSA (r16 lesson) ----
#define LOADQ(S, KH_) do {                                                     \
    const int gh_  = h0 + y8 + (KH_) - PAD;                                    \
    const int ghc_ = gh_ < 0 ? 0 : (gh_ > H_ - 1 ? H_ - 1 : gh_);              \
    const float* rp_ = xc + (size_t)ghc_ * W_;                                 \
    if (ledge) {                                                               \
        const f32x4* vp_ = (const f32x4*)rp_;                                  \
        q##S##0 = vp_[0]; q##S##1 = vp_[1]; q##S##2 = vp_[2];                  \
    } else if (redge) {                                                        \
        const f32x4* vp_ = (const f32x4*)(rp_ + 116);                          \
        q##S##0 = vp_[0]; q##S##1 = vp_[1]; q##S##2 = vp_[2];                  \
    } else {                                                                   \
        const f32x4* vp_ = (const f32x4*)(rp_ + w0 + xh * 8 - 4);              \
        q##S##0 = vp_[0]; q##S##1 = vp_[1]; q##S##2 = vp_[2]; q##S##3 = vp_[3];\
    }                                                                          \
} while (0)

#define PACKD(S) do {                                                          \
    if (ledge) {                                                               \
        d##S##0 = 0u;                                                          \
        d##S##1 = pk2(0.f, q##S##0[0]);                                        \
        d##S##2 = pk2(q##S##0[1], q##S##0[2]);                                 \
        d##S##3 = pk2(q##S##0[3], q##S##1[0]);                                 \
        d##S##4 = pk2(q##S##1[1], q##S##1[2]);                                 \
        d##S##5 = pk2(q##S##1[3], q##S##2[0]);                                 \
        d##S##6 = pk2(q##S##2[1], q##S##2[2]);                                 \
    } else if (redge) {                                                        \
        d##S##0 = pk2(q##S##0[1], q##S##0[2]);                                 \
        d##S##1 = pk2(q##S##0[3], q##S##1[0]);                                 \
        d##S##2 = pk2(q##S##1[1], q##S##1[2]);                                 \
        d##S##3 = pk2(q##S##1[3], q##S##2[0]);                                 \
        d##S##4 = pk2(q##S##2[1], q##S##2[2]);                                 \
        d##S##5 = pk2(q##S##2[3], 0.f);                                        \
        d##S##6 = 0u;                                                          \
    } else {                                                                   \
        d##S##0 = pk2(q##S##0[1], q##S##0[2]);                                 \
        d##S##1 = pk2(q##S##0[3], q##S##1[0]);                                 \
        d##S##2 = pk2(q##S##1[1], q##S##1[2]);                                 \
        d##S##3 = pk2(q##S##1[3], q##S##2[0]);                                 \
        d##S##4 = pk2(q##S##2[1], q##S##2[2]);                                 \
        d##S##5 = pk2(q##S##2[3], q##S##3[0]);                                 \
        d##S##6 = pk2(q##S##3[1], q##S##3[2]);                                 \
    }                                                                          \
} while (0)

#define FMAD(S, KH_) do {                                                      \
    const int gh_ = h0 + y8 + (KH_) - PAD;                                     \
    if (gh_ >= 0 && gh_ < H_) {                                                \
        const int zo_ = (KH_) * ZKHB;                                          \
        const unsigned r0_ = AB(d##S##1, d##S##0);                             \
        const unsigned r1_ = AB(d##S##2, d##S##1);                             \
        const unsigned r2_ = AB(d##S##3, d##S##2);                             \
        const unsigned r3_ = AB(d##S##4, d##S##3);                             \
        const unsigned r4_ = AB(d##S##5, d##S##4);                             \
        const unsigned r5_ = AB(d##S##6, d##S##5);                             \
        const unsigned r6_ = AB(d##S##6, d##S##6);                             \
        u32x4 q_;                                                              \
        q_ = *(const u32x4*)(zp0 + zo_);                                       \
        a0 = DOT2(ash2(q_[0]), ash2(d##S##0), a0);                             \
        a0 = DOT2(ash2(q_[1]), ash2(d##S##1), a0);                             \
        a0 = DOT2(ash2(q_[2]), ash2(d##S##2), a0);                             \
        a0 = DOT2(ash2(q_[3]), ash2(d##S##3), a0);                             \
        q_ = *(const u32x4*)(zp1 + zo_);                                       \
        a1 = DOT2(ash2(q_[0]), ash2(r0_), a1);                                 \
        a1 = DOT2(ash2(q_[1]), ash2(r1_), a1);                                 \
        a1 = DOT2(ash2(q_[2]), ash2(r2_), a1);                                 \
        a1 = DOT2(ash2(q_[3]), ash2(r3_), a1);                                 \
        q_ = *(const u32x4*)(zp2 + zo_);                                       \
        a2 = DOT2(ash2(q_[0]), ash2(d##S##1), a2);                             \
        a2 = DOT2(ash2(q_[1]), ash2(d##S##2), a2);                             \
        a2 = DOT2(ash2(q_[2]), ash2(d##S##3), a2);                             \
        a2 = DOT2(ash2(q_[3]), ash2(d##S##4), a2);                             \
        q_ = *(const u32x4*)(zp3 + zo_);                                       \
        a3 = DOT2(ash2(q_[0]), ash2(r1_), a3);                                 \
        a3 = DOT2(ash2(q_[1]), ash2(r2_), a3);                                 \
        a3 = DOT2(ash2(q_[2]), ash2(r3_), a3);                                 \
        a3 = DOT2(ash2(q_[3]), ash2(r4_), a3);                                 \
        q_ = *(const u32x4*)(zp4 + zo_);                                       \
        a4 = DOT2(ash2(q_[0]), ash2(d##S##2), a4);                             \
        a4 = DOT2(ash2(q_[1]), ash2(d##S##3), a4);                             \
        a4 = DOT2(ash2(q_[2]), ash2(d##S##4), a4);                             \
        a4 = DOT2(ash2(q_[3]), ash2(d##S##5), a4);                             \
        q_ = *(const u32x4*)(zp5 + zo_);                                       \
        a5 = DOT2(ash2(q_[0]), ash2(r2_), a5);                                 \
        a5 = DOT2(ash2(q_[1]), ash2(r3_), a5);                                 \
        a5 = DOT2(ash2(q_[2]), ash2(r4_), a5);                                 \
        a5 = DOT2(ash2(q_[3]), ash2(r5_), a5);                                 \
        q_ = *(const u32x4*)(zp6 + zo_);                                       \
        a6 = DOT2(ash2(q_[0]), ash2(d##S##3), a6);                             \
        a6 = DOT2(ash2(q_[1]), ash2(d##S##4), a6);                             \
        a6 = DOT2(ash2(q_[2]), ash2(d##S##5), a6);                             \
        a6 = DOT2(ash2(q_[3]), ash2(d##S##6), a6);                             \
        q_ = *(const u32x4*)(zp7 + zo_);                                       \
        a7 = DOT2(ash2(q_[0]), ash2(r3_), a7);                                 \
        a7 = DOT2(ash2(q_[1]), ash2(r4_), a7);                                 \
        a7 = DOT2(ash2(q_[2]), ash2(r5_), a7);                                 \
        a7 = DOT2(ash2(q_[3]), ash2(r6_), a7);                                 \
    }                                                                          \
} while (0)

// ======== r26 kernel, single change: launch_bounds (256,4) -> (256,6) ======
// Occupancy as the last untested single variable. LDS 23.9KB x 6 = 143KB OK;
// VGPR cap ~85 vs ~64-80 demand. Watch WRITE_SIZE for the spill signature.
__global__ __launch_bounds__(256, 6) void invol_fused19(
    const float* __restrict__ x,
    const float* __restrict__ cw,
    const float* __restrict__ bng,
    const float* __restrict__ bnb,
    const float* __restrict__ bnm,
    const float* __restrict__ bnv,
    float* __restrict__ out)
{
    __shared__ __align__(16) char lds[LDSZ];

    const int tid  = threadIdx.x;
    const int lane = tid & 63;
    const int wv   = tid >> 6;
    const int l15  = lane & 15;
    const int l4   = lane >> 4;

    // XCD-locality swizzle (r13: FETCH 37->27 MB)
    const int bid = blockIdx.x;
    const int xcd = bid & 7;
    const int s   = bid >> 3;
    const int b   = xcd >> 1;
    const int g   = (xcd & 1) * 2 + (s >> 7);
    const int by  = (s >> 3) & 15;
    const int bx  = s & 7;
    const int w0  = bx * TW;
    const int h0  = by * TH;

    // wave-synchronous consumer map (r18: wave consumes its own z rows)
    const int y8 = tid >> 5;           // wave = y8>>1 (= wv)
    const int c2 = (tid >> 1) & 15;
    const int xh = tid & 1;
    const bool ledge = (bx == 0) & (xh == 0);
    const bool redge = (bx == W_ / TW - 1) & (xh == 1);
    const float* xc = x + (size_t)(b * C_ + g * GC_ + c2) * HW_;

    f32x4 qA0 = {0,0,0,0}, qA1 = {0,0,0,0}, qA2 = {0,0,0,0}, qA3 = {0,0,0,0};
    f32x4 qB0 = {0,0,0,0}, qB1 = {0,0,0,0}, qB2 = {0,0,0,0}, qB3 = {0,0,0,0};
    unsigned dA0, dA1, dA2, dA3, dA4, dA5, dA6;
    unsigned dB0, dB1, dB2, dB3, dB4, dB5, dB6;

    LOADQ(A, 0);   // first involution row in flight under the whole conv phase

    // ---- stage w-tile + folded sc/sb ----
    if (tid < KK) {
        const int o = g * KK + tid;
        const float scv = bng[o] * rsqrtf(bnv[o] + 1e-5f);
        *(float*)(lds + SCOFF + tid * 4) = scv;
        *(float*)(lds + SBOFF + tid * 4) = bnb[o] - bnm[o] * scv;
    }
    __builtin_amdgcn_s_barrier();   // scale visible for w-fold below
    {
        const float* cwg = cw + (size_t)g * KK * C_;
        const int c  = tid & 63;
        const int kb = tid >> 6;
#pragma unroll
        for (int it = 0; it < 16; ++it) {
            const int k = it * 4 + kb;
            float v = 0.f;
            if (k < KK)
                v = cwg[k * C_ + c] * *(const float*)(lds + SCOFF + k * 4);
            *(unsigned short*)(lds + WOFF + k * 136 + c * 2) = (unsigned short)f2bf(v);
        }
    }

    // ---- A fragments: direct gather from global x (r13-proven pattern) ----
    bf16x8 afr[2][2];
    {
        const float* xb = x + (size_t)b * C_ * HW_;
#pragma unroll
        for (int mt = 0; mt < 2; ++mt) {
            const int hh = h0 + wv * 2 + mt;
            const float* xp = xb + hh * W_ + (w0 + l15);
#pragma unroll
            for (int ks = 0; ks < 2; ++ks) {
                const int c0 = ks * 32 + l4 * 8;
                bf16x8 a;
#pragma unroll
                for (int j = 0; j < 8; ++j)
                    a[j] = (short)f2bf(xp[(size_t)(c0 + j) * HW_]);
                afr[mt][ks] = a;
            }
        }
    }

    __syncthreads();   // w-tile staged

    // ---- B fragments from w-tile ----
    bf16x8 bfr[4][2];
#pragma unroll
    for (int nt = 0; nt < 4; ++nt) {
        const int k = nt * 16 + l15;
        const char* base_ = lds + WOFF + k * 136;
#pragma unroll
        for (int ks = 0; ks < 2; ++ks) {
            const char* pB = base_ + ks * 64 + l4 * 16;
            const bf16x4 lo = *(const bf16x4*)(pB);
            const bf16x4 hi = *(const bf16x4*)(pB + 8);
            bf16x8 f;
            f[0] = lo[0]; f[1] = lo[1]; f[2] = lo[2]; f[3] = lo[3];
            f[4] = hi[0]; f[5] = hi[1]; f[6] = hi[2]; f[7] = hi[3];
            bfr[nt][ks] = f;
        }
    }

    // ---- MFMA: z rows {2wv, 2wv+1} ----
    f32x4 acc1[2][4];
#pragma unroll
    for (int mt = 0; mt < 2; ++mt)
#pragma unroll
        for (int nt = 0; nt < 4; ++nt) {
            f32x4 a = {0.f, 0.f, 0.f, 0.f};
            a = __builtin_amdgcn_mfma_f32_16x16x32_bf16(afr[mt][0], bfr[nt][0], a, 0, 0, 0);
            a = __builtin_amdgcn_mfma_f32_16x16x32_bf16(afr[mt][1], bfr[nt][1], a, 0, 0, 0);
            acc1[mt][nt] = a;
        }

    // ---- epilogue: +bias, SiLU -> f16 -> swizzled z (wave's own rows) ----
#pragma unroll
    for (int nt = 0; nt < 4; ++nt) {
        const int k = nt * 16 + l15;
        if (k < KK) {
            const int kh = (k * 9363) >> 16;        // k/7
            const int kw = k - kh * 7;
            const int kbase = kh * ZKHB + kw * 2;
            const float bi = *(const float*)(lds + SBOFF + k * 4);
#pragma unroll
            for (int mt = 0; mt < 2; ++mt) {
                const int px0 = (wv * 2 + mt) * 16 + l4 * 4;
#pragma unroll
                for (int r = 0; r < 4; ++r) {
                    const int px = px0 + r;
                    const int sw = (px << 4) ^ (((px >> 3) & 7) << 4);
                    const float t = acc1[mt][nt][r] + bi;
                    const float v = __fdividef(t, 1.0f + __expf(-t));
                    *(unsigned short*)(lds + kbase + sw) = f16b(v);
                }
            }
        } else if (k < 56) {                        // zero the 8th-tap pad
            const int khp = k - KK;
#pragma unroll
            for (int mt = 0; mt < 2; ++mt) {
                const int px0 = (wv * 2 + mt) * 16 + l4 * 4;
#pragma unroll
                for (int r = 0; r < 4; ++r) {
                    const int px = px0 + r;
                    const int sw = (px << 4) ^ (((px >> 3) & 7) << 4);
                    *(unsigned short*)(lds + khp * ZKHB + sw + 14) = 0;
                }
            }
        }
    }

    // NO barrier: consumer map keeps each wave on the z rows it just wrote
    // (wave-internal LDS ops are in-order, r18-proven).

    // ---- involution: f16 dot2, 2-deep row pipeline (r17 exact) ----
    float a0 = 0.f, a1 = 0.f, a2 = 0.f, a3 = 0.f;
    float a4 = 0.f, a5 = 0.f, a6 = 0.f, a7 = 0.f;

    const int pxb = y8 * 16 + xh * 8;
    const int mx  = ((2 * y8 + xh) & 7) << 4;
    const char* zbase = lds + (pxb << 4);
    const char* zp0 = zbase + ((0 << 4) ^ mx);
    const char* zp1 = zbase + ((1 << 4) ^ mx);
    const char* zp2 = zbase + ((2 << 4) ^ mx);
    const char* zp3 = zbase + ((3 << 4) ^ mx);
    const char* zp4 = zbase + ((4 << 4) ^ mx);
    const char* zp5 = zbase + ((5 << 4) ^ mx);
    const char* zp6 = zbase + ((6 << 4) ^ mx);
    const char* zp7 = zbase + ((7 << 4) ^ mx);

#pragma unroll 1
    for (int kh2 = 0; kh2 < 3; ++kh2) {             // kh rolled (r4 spill lesson)
        LOADQ(B, 2 * kh2 + 1);
        PACKD(A); FMAD(A, 2 * kh2);
        LOADQ(A, 2 * kh2 + 2);
        PACKD(B); FMAD(B, 2 * kh2 + 1);
    }
    PACKD(A); FMAD(A, 6);

    float* og = out + (size_t)(b * C_ + g * GC_ + c2) * HW_
                    + (h0 + y8) * W_ + w0 + xh * 8;
    {
        f32x4 v;
        v[0] = a0; v[1] = a1; v[2] = a2; v[3] = a3;
        *(f32x4*)(og + 0) = v;
        v[0] = a4; v[1] = a5; v[2] = a6; v[3] = a7;
        *(f32x4*)(og + 4) = v;
    }
}

extern "C" void kernel_launch(void* const* d_in, const int* in_sizes, int n_in,
                              void* d_out, int out_size, void* d_ws, size_t ws_size,
                              hipStream_t stream) {
    const float* x   = (const float*)d_in[0];
    const float* cw  = (const float*)d_in[1];
    const float* bng = (const float*)d_in[2];
    const float* bnb = (const float*)d_in[3];
    const float* bnm = (const float*)d_in[4];
    const float* bnv = (const float*)d_in[5];
    float* out = (float*)d_out;

    invol_fused19<<<dim3(2048), dim3(256), 0, stream>>>(x, cw, bng, bnb, bnm,
                                                        bnv, out);
}

// Round 29
// 33.472 us; speedup vs baseline: 1.7161x; 1.7161x over previous
//
#include <hip/hip_runtime.h>

#define B_   4
#define C_   64
#define H_   128
#define W_   128
#define KS   7
#define G_   4
#define GC_  16
#define KK   49
#define PAD  3
#define TH   8
#define TW   16
#define HW_  (H_ * W_)
#define ZKHB 2112              // bytes per kh plane: 128px*16B + 64B bank shift

// LDS layout (bytes): z [0, 14784) | w-tile [14784, 23488) | sc/sb
#define WOFF  14784            // w-tile [64k][68 bf16] stride 136B = 8704
#define SCOFF 23488            // folded scale, 49 f32
#define SBOFF 23688            // folded bias,  49 f32
#define LDSZ  23888

typedef float f32x4  __attribute__((ext_vector_type(4)));
typedef short bf16x8 __attribute__((ext_vector_type(8)));
typedef short bf16x4 __attribute__((ext_vector_type(4)));
typedef unsigned int u32x4 __attribute__((ext_vector_type(4)));
typedef __fp16 h16x2 __attribute__((ext_vector_type(2)));

__device__ __forceinline__ unsigned f2bf(float f) {
    unsigned u = __float_as_uint(f);
    unsigned r = u + 0x7FFFu + ((u >> 16) & 1u);
    return r >> 16;
}
__device__ __forceinline__ unsigned pk2(float a, float b) {
    union { h16x2 h; unsigned u; } x;
    x.h = __builtin_amdgcn_cvt_pkrtz(a, b);
    return x.u;
}
__device__ __forceinline__ h16x2 ash2(unsigned u) {
    union { unsigned u; h16x2 h; } x; x.u = u; return x.h;
}
__device__ __forceinline__ unsigned short f16b(float f) {
    union { __fp16 h; unsigned short s; } x; x.h = (__fp16)f; return x.s;
}
#if __has_builtin(__builtin_amdgcn_fdot2)
#define DOT2(a, b, c) __builtin_amdgcn_fdot2((a), (b), (c), false)
#else
#define DOT2(a, b, c) ((c) + (float)(a)[0] * (float)(b)[0] + (float)(a)[1] * (float)(b)[1])
#endif
#define AB(a, b) __builtin_amdgcn_alignbit((a), (b), 16)

// ---- involution phase macros: pure named-SSA (r16 lesson) ----
#define LOADQ(S, KH_) do {                                                     \
    const int gh_  = h0 + y8 + (KH_) - PAD;                                    \
    const int ghc_ = gh_ < 0 ? 0 : (gh_ > H_ - 1 ? H_ - 1 : gh_);              \
    const float* rp_ = xc + (size_t)ghc_ * W_;                                 \
    if (ledge) {                                                               \
        const f32x4* vp_ = (const f32x4*)rp_;                                  \
        q##S##0 = vp_[0]; q##S##1 = vp_[1]; q##S##2 = vp_[2];                  \
    } else if (redge) {                                                        \
        const f32x4* vp_ = (const f32x4*)(rp_ + 116);                          \
        q##S##0 = vp_[0]; q##S##1 = vp_[1]; q##S##2 = vp_[2];                  \
    } else {                                                                   \
        const f32x4* vp_ = (const f32x4*)(rp_ + w0 + xh * 8 - 4);              \
        q##S##0 = vp_[0]; q##S##1 = vp_[1]; q##S##2 = vp_[2]; q##S##3 = vp_[3];\
    }                                                                          \
} while (0)

#define PACKD(S) do {                                                          \
    if (ledge) {                                                               \
        d##S##0 = 0u;                                                          \
        d##S##1 = pk2(0.f, q##S##0[0]);                                        \
        d##S##2 = pk2(q##S##0[1], q##S##0[2]);                                 \
        d##S##3 = pk2(q##S##0[3], q##S##1[0]);                                 \
        d##S##4 = pk2(q##S##1[1], q##S##1[2]);                                 \
        d##S##5 = pk2(q##S##1[3], q##S##2[0]);                                 \
        d##S##6 = pk2(q##S##2[1], q##S##2[2]);                                 \
    } else if (redge) {                                                        \
        d##S##0 = pk2(q##S##0[1], q##S##0[2]);                                 \
        d##S##1 = pk2(q##S##0[3], q##S##1[0]);                                 \
        d##S##2 = pk2(q##S##1[1], q##S##1[2]);                                 \
        d##S##3 = pk2(q##S##1[3], q##S##2[0]);                                 \
        d##S##4 = pk2(q##S##2[1], q##S##2[2]);                                 \
        d##S##5 = pk2(q##S##2[3], 0.f);                                        \
        d##S##6 = 0u;                                                          \
    } else {                                                                   \
        d##S##0 = pk2(q##S##0[1], q##S##0[2]);                                 \
        d##S##1 = pk2(q##S##0[3], q##S##1[0]);                                 \
        d##S##2 = pk2(q##S##1[1], q##S##1[2]);                                 \
        d##S##3 = pk2(q##S##1[3], q##S##2[0]);                                 \
        d##S##4 = pk2(q##S##2[1], q##S##2[2]);                                 \
        d##S##5 = pk2(q##S##2[3], q##S##3[0]);                                 \
        d##S##6 = pk2(q##S##3[1], q##S##3[2]);                                 \
    }                                                                          \
} while (0)

#define FMAD(S, KH_) do {                                                      \
    const int gh_ = h0 + y8 + (KH_) - PAD;                                     \
    if (gh_ >= 0 && gh_ < H_) {                                                \
        const int zo_ = (KH_) * ZKHB;                                          \
        const unsigned r0_ = AB(d##S##1, d##S##0);                             \
        const unsigned r1_ = AB(d##S##2, d##S##1);                             \
        const unsigned r2_ = AB(d##S##3, d##S##2);                             \
        const unsigned r3_ = AB(d##S##4, d##S##3);                             \
        const unsigned r4_ = AB(d##S##5, d##S##4);                             \
        const unsigned r5_ = AB(d##S##6, d##S##5);                             \
        const unsigned r6_ = AB(d##S##6, d##S##6);                             \
        u32x4 q_;                                                              \
        q_ = *(const u32x4*)(zp0 + zo_);                                       \
        a0 = DOT2(ash2(q_[0]), ash2(d##S##0), a0);                             \
        a0 = DOT2(ash2(q_[1]), ash2(d##S##1), a0);                             \
        a0 = DOT2(ash2(q_[2]), ash2(d##S##2), a0);                             \
        a0 = DOT2(ash2(q_[3]), ash2(d##S##3), a0);                             \
        q_ = *(const u32x4*)(zp1 + zo_);                                       \
        a1 = DOT2(ash2(q_[0]), ash2(r0_), a1);                                 \
        a1 = DOT2(ash2(q_[1]), ash2(r1_), a1);                                 \
        a1 = DOT2(ash2(q_[2]), ash2(r2_), a1);                                 \
        a1 = DOT2(ash2(q_[3]), ash2(r3_), a1);                                 \
        q_ = *(const u32x4*)(zp2 + zo_);                                       \
        a2 = DOT2(ash2(q_[0]), ash2(d##S##1), a2);                             \
        a2 = DOT2(ash2(q_[1]), ash2(d##S##2), a2);                             \
        a2 = DOT2(ash2(q_[2]), ash2(d##S##3), a2);                             \
        a2 = DOT2(ash2(q_[3]), ash2(d##S##4), a2);                             \
        q_ = *(const u32x4*)(zp3 + zo_);                                       \
        a3 = DOT2(ash2(q_[0]), ash2(r1_), a3);                                 \
        a3 = DOT2(ash2(q_[1]), ash2(r2_), a3);                                 \
        a3 = DOT2(ash2(q_[2]), ash2(r3_), a3);                                 \
        a3 = DOT2(ash2(q_[3]), ash2(r4_), a3);                                 \
        q_ = *(const u32x4*)(zp4 + zo_);                                       \
        a4 = DOT2(ash2(q_[0]), ash2(d##S##2), a4);                             \
        a4 = DOT2(ash2(q_[1]), ash2(d##S##3), a4);                             \
        a4 = DOT2(ash2(q_[2]), ash2(d##S##4), a4);                             \
        a4 = DOT2(ash2(q_[3]), ash2(d##S##5), a4);                             \
        q_ = *(const u32x4*)(zp5 + zo_);                                       \
        a5 = DOT2(ash2(q_[0]), ash2(r2_), a5);                                 \
        a5 = DOT2(ash2(q_[1]), ash2(r3_), a5);                                 \
        a5 = DOT2(ash2(q_[2]), ash2(r4_), a5);                                 \
        a5 = DOT2(ash2(q_[3]), ash2(r5_), a5);                                 \
        q_ = *(const u32x4*)(zp6 + zo_);                                       \
        a6 = DOT2(ash2(q_[0]), ash2(d##S##3), a6);                             \
        a6 = DOT2(ash2(q_[1]), ash2(d##S##4), a6);                             \
        a6 = DOT2(ash2(q_[2]), ash2(d##S##5), a6);                             \
        a6 = DOT2(ash2(q_[3]), ash2(d##S##6), a6);                             \
        q_ = *(const u32x4*)(zp7 + zo_);                                       \
        a7 = DOT2(ash2(q_[0]), ash2(r3_), a7);                                 \
        a7 = DOT2(ash2(q_[1]), ash2(r4_), a7);                                 \
        a7 = DOT2(ash2(q_[2]), ash2(r5_), a7);                                 \
        a7 = DOT2(ash2(q_[3]), ash2(r6_), a7);                                 \
    }                                                                          \
} while (0)

// ======== final kernel: r26 + race fix ========
// r28 caught a cross-wave race: raw s_barrier between the tid<49 sc/sb LDS
// writes and the all-wave w-fold reads does NOT fence LDS (ISA: "s_waitcnt
// first if data dep!"); waves 1-3 could read the previous block's scales.
// Fix: __syncthreads() (waitcnt + barrier). The z handoff stays barrier-free
// (same-wave in-order LDS: producer rows {2wv,2wv+1} == consumer rows).
__global__ __launch_bounds__(256, 4) void invol_fused20(
    const float* __restrict__ x,
    const float* __restrict__ cw,
    const float* __restrict__ bng,
    const float* __restrict__ bnb,
    const float* __restrict__ bnm,
    const float* __restrict__ bnv,
    float* __restrict__ out)
{
    __shared__ __align__(16) char lds[LDSZ];

    const int tid  = threadIdx.x;
    const int lane = tid & 63;
    const int wv   = tid >> 6;
    const int l15  = lane & 15;
    const int l4   = lane >> 4;

    // XCD-locality swizzle (r13: FETCH 37->27 MB)
    const int bid = blockIdx.x;
    const int xcd = bid & 7;
    const int s   = bid >> 3;
    const int b   = xcd >> 1;
    const int g   = (xcd & 1) * 2 + (s >> 7);
    const int by  = (s >> 3) & 15;
    const int bx  = s & 7;
    const int w0  = bx * TW;
    const int h0  = by * TH;

    // wave-synchronous consumer map (r18: wave consumes its own z rows)
    const int y8 = tid >> 5;           // wave = y8>>1 (= wv)
    const int c2 = (tid >> 1) & 15;
    const int xh = tid & 1;
    const bool ledge = (bx == 0) & (xh == 0);
    const bool redge = (bx == W_ / TW - 1) & (xh == 1);
    const float* xc = x + (size_t)(b * C_ + g * GC_ + c2) * HW_;

    f32x4 qA0 = {0,0,0,0}, qA1 = {0,0,0,0}, qA2 = {0,0,0,0}, qA3 = {0,0,0,0};
    f32x4 qB0 = {0,0,0,0}, qB1 = {0,0,0,0}, qB2 = {0,0,0,0}, qB3 = {0,0,0,0};
    unsigned dA0, dA1, dA2, dA3, dA4, dA5, dA6;
    unsigned dB0, dB1, dB2, dB3, dB4, dB5, dB6;

    LOADQ(A, 0);   // first involution row in flight under the whole conv phase

    // ---- stage folded sc/sb, then fence properly before cross-wave reads ----
    if (tid < KK) {
        const int o = g * KK + tid;
        const float scv = bng[o] * rsqrtf(bnv[o] + 1e-5f);
        *(float*)(lds + SCOFF + tid * 4) = scv;
        *(float*)(lds + SBOFF + tid * 4) = bnb[o] - bnm[o] * scv;
    }
    __syncthreads();   // RACE FIX (r28): waitcnt+barrier so sc/sb are visible
    {
        const float* cwg = cw + (size_t)g * KK * C_;
        const int c  = tid & 63;
        const int kb = tid >> 6;
#pragma unroll
        for (int it = 0; it < 16; ++it) {
            const int k = it * 4 + kb;
            float v = 0.f;
            if (k < KK)
                v = cwg[k * C_ + c] * *(const float*)(lds + SCOFF + k * 4);
            *(unsigned short*)(lds + WOFF + k * 136 + c * 2) = (unsigned short)f2bf(v);
        }
    }

    // ---- A fragments: direct gather from global x (r13-proven pattern) ----
    bf16x8 afr[2][2];
    {
        const float* xb = x + (size_t)b * C_ * HW_;
#pragma unroll
        for (int mt = 0; mt < 2; ++mt) {
            const int hh = h0 + wv * 2 + mt;
            const float* xp = xb + hh * W_ + (w0 + l15);
#pragma unroll
            for (int ks = 0; ks < 2; ++ks) {
                const int c0 = ks * 32 + l4 * 8;
                bf16x8 a;
#pragma unroll
                for (int j = 0; j < 8; ++j)
                    a[j] = (short)f2bf(xp[(size_t)(c0 + j) * HW_]);
                afr[mt][ks] = a;
            }
        }
    }

    __syncthreads();   // w-tile staged

    // ---- B fragments from w-tile ----
    bf16x8 bfr[4][2];
#pragma unroll
    for (int nt = 0; nt < 4; ++nt) {
        const int k = nt * 16 + l15;
        const char* base_ = lds + WOFF + k * 136;
#pragma unroll
        for (int ks = 0; ks < 2; ++ks) {
            const char* pB = base_ + ks * 64 + l4 * 16;
            const bf16x4 lo = *(const bf16x4*)(pB);
            const bf16x4 hi = *(const bf16x4*)(pB + 8);
            bf16x8 f;
            f[0] = lo[0]; f[1] = lo[1]; f[2] = lo[2]; f[3] = lo[3];
            f[4] = hi[0]; f[5] = hi[1]; f[6] = hi[2]; f[7] = hi[3];
            bfr[nt][ks] = f;
        }
    }

    // ---- MFMA: z rows {2wv, 2wv+1} ----
    f32x4 acc1[2][4];
#pragma unroll
    for (int mt = 0; mt < 2; ++mt)
#pragma unroll
        for (int nt = 0; nt < 4; ++nt) {
            f32x4 a = {0.f, 0.f, 0.f, 0.f};
            a = __builtin_amdgcn_mfma_f32_16x16x32_bf16(afr[mt][0], bfr[nt][0], a, 0, 0, 0);
            a = __builtin_amdgcn_mfma_f32_16x16x32_bf16(afr[mt][1], bfr[nt][1], a, 0, 0, 0);
            acc1[mt][nt] = a;
        }

    // ---- epilogue: +bias, SiLU -> f16 -> swizzled z (wave's own rows) ----
#pragma unroll
    for (int nt = 0; nt < 4; ++nt) {
        const int k = nt * 16 + l15;
        if (k < KK) {
            const int kh = (k * 9363) >> 16;        // k/7
            const int kw = k - kh * 7;
            const int kbase = kh * ZKHB + kw * 2;
            const float bi = *(const float*)(lds + SBOFF + k * 4);
#pragma unroll
            for (int mt = 0; mt < 2; ++mt) {
                const int px0 = (wv * 2 + mt) * 16 + l4 * 4;
#pragma unroll
                for (int r = 0; r < 4; ++r) {
                    const int px = px0 + r;
                    const int sw = (px << 4) ^ (((px >> 3) & 7) << 4);
                    const float t = acc1[mt][nt][r] + bi;
                    const float v = __fdividef(t, 1.0f + __expf(-t));
                    *(unsigned short*)(lds + kbase + sw) = f16b(v);
                }
            }
        } else if (k < 56) {                        // zero the 8th-tap pad
            const int khp = k - KK;
#pragma unroll
            for (int mt = 0; mt < 2; ++mt) {
                const int px0 = (wv * 2 + mt) * 16 + l4 * 4;
#pragma unroll
                for (int r = 0; r < 4; ++r) {
                    const int px = px0 + r;
                    const int sw = (px << 4) ^ (((px >> 3) & 7) << 4);
                    *(unsigned short*)(lds + khp * ZKHB + sw + 14) = 0;
                }
            }
        }
    }

    // NO barrier here: each wave consumes exactly the z rows it wrote
    // (same-wave LDS ops are in-order -- r18-proven, race-free by construction).

    // ---- involution: f16 dot2, 2-deep row pipeline (r17 exact) ----
    float a0 = 0.f, a1 = 0.f, a2 = 0.f, a3 = 0.f;
    float a4 = 0.f, a5 = 0.f, a6 = 0.f, a7 = 0.f;

    const int pxb = y8 * 16 + xh * 8;
    const int mx  = ((2 * y8 + xh) & 7) << 4;
    const char* zbase = lds + (pxb << 4);
    const char* zp0 = zbase + ((0 << 4) ^ mx);
    const char* zp1 = zbase + ((1 << 4) ^ mx);
    const char* zp2 = zbase + ((2 << 4) ^ mx);
    const char* zp3 = zbase + ((3 << 4) ^ mx);
    const char* zp4 = zbase + ((4 << 4) ^ mx);
    const char* zp5 = zbase + ((5 << 4) ^ mx);
    const char* zp6 = zbase + ((6 << 4) ^ mx);
    const char* zp7 = zbase + ((7 << 4) ^ mx);

#pragma unroll 1
    for (int kh2 = 0; kh2 < 3; ++kh2) {             // kh rolled (r4 spill lesson)
        LOADQ(B, 2 * kh2 + 1);
        PACKD(A); FMAD(A, 2 * kh2);
        LOADQ(A, 2 * kh2 + 2);
        PACKD(B); FMAD(B, 2 * kh2 + 1);
    }
    PACKD(A); FMAD(A, 6);

    float* og = out + (size_t)(b * C_ + g * GC_ + c2) * HW_
                    + (h0 + y8) * W_ + w0 + xh * 8;
    {
        f32x4 v;
        v[0] = a0; v[1] = a1; v[2] = a2; v[3] = a3;
        *(f32x4*)(og + 0) = v;
        v[0] = a4; v[1] = a5; v[2] = a6; v[3] = a7;
        *(f32x4*)(og + 4) = v;
    }
}

extern "C" void kernel_launch(void* const* d_in, const int* in_sizes, int n_in,
                              void* d_out, int out_size, void* d_ws, size_t ws_size,
                              hipStream_t stream) {
    const float* x   = (const float*)d_in[0];
    const float* cw  = (const float*)d_in[1];
    const float* bng = (const float*)d_in[2];
    const float* bnb = (const float*)d_in[3];
    const float* bnm = (const float*)d_in[4];
    const float* bnv = (const float*)d_in[5];
    float* out = (float*)d_out;

    invol_fused20<<<dim3(2048), dim3(256), 0, stream>>>(x, cw, bng, bnb, bnm,
                                                        bnv, out);
}